// Round 1
// baseline (572.304 us; speedup 1.0000x reference)
//
#include <hip/hip_runtime.h>
#include <hip/hip_fp16.h>

#define N_POINTS 500000
#define BN_EPS 1e-5f
#define A_COEF -0.75f

// -------- workspace layout (float offsets) --------
// total bytes = 25316352 + 6291456 = ~31.6 MB
#define WS_W_OFF      0                         // reordered weights [ic][ky][kx][oc] : 36864
#define WS_CONV_OFF   36864                     // conv+bias HWC [3][128][128][64]    : 3145728
#define WS_POOL_OFF   (WS_CONV_OFF + 3145728)   // pooled  HWC [3][128][128][64]      : 3145728
#define WS_SUM_OFF    (WS_POOL_OFF + 3145728)   // [3][64] sums                       : 192
#define WS_SUMSQ_OFF  (WS_SUM_OFF + 192)        // [3][64] sumsq                      : 192
#define WS_SCALE_OFF  (WS_SUMSQ_OFF + 192)      // [3][64]                            : 192
#define WS_SHIFT_OFF  (WS_SCALE_OFF + 192)      // [3][64]                            : 192
#define WS_PLANES_OFF (WS_SHIFT_OFF + 192)      // fp16 planes HWC [3][128][128][64] (as __half)

// ================= prep: transpose weights [oc][ic][3][3] -> [ic][k][oc]; zero stat accumulators
__global__ __launch_bounds__(256) void prep_kernel(const float* __restrict__ w_in,
                                                   float* __restrict__ ws) {
  int i = blockIdx.x * 256 + threadIdx.x;
  if (i < 36864) {
    int oc = i & 63;
    int rest = i >> 6;        // ic*9 + kk
    int kk = rest % 9;
    int ic = rest / 9;
    ws[WS_W_OFF + i] = w_in[(oc * 64 + ic) * 9 + kk];
  }
  if (i < 384) ws[WS_SUM_OFF + i] = 0.0f;  // sums + sumsq contiguous
}

// ================= conv3x3 stride2 pad1 + bias, output HWC fp32
// grid (2, 128, 3): x-half, output row, plane. 256 thr = 4 waves; wave handles 16 px, lane = oc.
#define ROWLEN 136
__global__ __launch_bounds__(256) void conv_kernel(const float* __restrict__ p0,
                                                   const float* __restrict__ p1,
                                                   const float* __restrict__ p2,
                                                   const float* __restrict__ bias,
                                                   float* __restrict__ ws) {
  __shared__ float lw[16 * 9 * 64];     // 36 KB
  __shared__ float li[16 * 3 * ROWLEN]; // 26.1 KB
  const int bx = blockIdx.x, oy = blockIdx.y, pz = blockIdx.z;
  const float* pin = (pz == 0) ? p0 : ((pz == 1) ? p1 : p2);
  const float* wre = ws + WS_W_OFF;
  const int t = threadIdx.x;
  const int lane = t & 63, wv = t >> 6;
  const int x0 = bx * 64;

  float acc[16];
#pragma unroll
  for (int p = 0; p < 16; p++) acc[p] = 0.0f;

  for (int cc = 0; cc < 4; cc++) {  // ic chunks of 16
    __syncthreads();
    // stage weights chunk (contiguous)
    const float* wsrc = wre + cc * 9216;
    for (int i = t; i < 9216; i += 256) lw[i] = wsrc[i];
    // stage input rows: [ic][r][j], x = 2*x0-2+j, iy = 2*oy+r-1 (zero pad)
    for (int idx = t; idx < 16 * 3 * ROWLEN; idx += 256) {
      int ic = idx / (3 * ROWLEN);
      int rem = idx - ic * 3 * ROWLEN;
      int r = rem / ROWLEN;
      int j = rem - r * ROWLEN;
      int x = 2 * x0 - 2 + j;
      int iy = 2 * oy + r - 1;
      float v = 0.0f;
      if (x >= 0 && x < 256 && iy >= 0 && iy < 256 && j < 134)
        v = pin[((cc * 16 + ic) * 256 + iy) * 256 + x];
      li[idx] = v;
    }
    __syncthreads();
#pragma unroll 1
    for (int ic = 0; ic < 16; ic++) {
      float w9[9];
#pragma unroll
      for (int k = 0; k < 9; k++) w9[k] = lw[(ic * 9 + k) * 64 + lane];
#pragma unroll
      for (int r = 0; r < 3; r++) {
        const float4* rowp = reinterpret_cast<const float4*>(&li[(ic * 3 + r) * ROWLEN + 32 * wv]);
        float vals[36];
#pragma unroll
        for (int q = 0; q < 9; q++) {
          float4 f = rowp[q];
          vals[4 * q] = f.x; vals[4 * q + 1] = f.y; vals[4 * q + 2] = f.z; vals[4 * q + 3] = f.w;
        }
#pragma unroll
        for (int p = 0; p < 16; p++) {
          acc[p] = fmaf(vals[2 * p + 1], w9[r * 3 + 0], acc[p]);
          acc[p] = fmaf(vals[2 * p + 2], w9[r * 3 + 1], acc[p]);
          acc[p] = fmaf(vals[2 * p + 3], w9[r * 3 + 2], acc[p]);
        }
      }
    }
  }
  const float b = bias[lane];
  const int px0 = x0 + wv * 16;
  float* cout = ws + WS_CONV_OFF;
#pragma unroll
  for (int p = 0; p < 16; p++)
    cout[((pz * 128 + oy) * 128 + (px0 + p)) * 64 + lane] = acc[p] + b;
}

// ================= avgpool 3x3 s2 p1 (count_include_pad) of raw input, output HWC fp32
#define PROWLEN 260
__global__ __launch_bounds__(256) void pool_kernel(const float* __restrict__ p0,
                                                   const float* __restrict__ p1,
                                                   const float* __restrict__ p2,
                                                   float* __restrict__ ws) {
  __shared__ float li[16 * 3 * PROWLEN];  // 49.9 KB
  const int oy = blockIdx.x, pz = blockIdx.y;
  const float* pin = (pz == 0) ? p0 : ((pz == 1) ? p1 : p2);
  float* pout = ws + WS_POOL_OFF;
  const int t = threadIdx.x;
  const int ic = t & 15, oxg = t >> 4;

  for (int cc = 0; cc < 4; cc++) {
    __syncthreads();
    for (int idx = t; idx < 16 * 3 * 258; idx += 256) {
      int c = idx / (3 * 258);
      int rem = idx - c * 3 * 258;
      int r = rem / 258;
      int j = rem - r * 258;       // x = j-1
      int x = j - 1;
      int iy = 2 * oy + r - 1;
      float v = 0.0f;
      if (x >= 0 && x < 256 && iy >= 0 && iy < 256)
        v = pin[((cc * 16 + c) * 256 + iy) * 256 + x];
      li[(c * 3 + r) * PROWLEN + j] = v;
    }
    __syncthreads();
#pragma unroll
    for (int o = 0; o < 8; o++) {
      int ox = oxg * 8 + o;
      float s = 0.0f;
#pragma unroll
      for (int r = 0; r < 3; r++) {
        int base = (ic * 3 + r) * PROWLEN + 2 * ox;  // j = 2*ox + kx
        s += li[base] + li[base + 1] + li[base + 2];
      }
      pout[((pz * 128 + oy) * 128 + ox) * 64 + cc * 16 + ic] = s * (1.0f / 9.0f);
    }
  }
}

// ================= BN stats: per (plane, channel) sum & sumsq over 16384
// grid 192: plane = b>>6, chunk = b&63 -> rows [chunk*256, +256)
__global__ __launch_bounds__(256) void stats_kernel(float* __restrict__ ws) {
  const int b = blockIdx.x;
  const int plane = b >> 6, chunk = b & 63;
  const int t = threadIdx.x;
  const int c = t & 63, g = t >> 6;
  const float* base = ws + WS_CONV_OFF + plane * (16384 * 64);
  float s = 0.0f, s2 = 0.0f;
  const int row0 = chunk * 256 + g * 64;
  for (int i = 0; i < 64; i++) {
    float v = base[(row0 + i) * 64 + c];
    s += v;
    s2 = fmaf(v, v, s2);
  }
  __shared__ float rs[256], rs2[256];
  rs[t] = s; rs2[t] = s2;
  __syncthreads();
  if (t < 64) {
    s = rs[t] + rs[t + 64] + rs[t + 128] + rs[t + 192];
    s2 = rs2[t] + rs2[t + 64] + rs2[t + 128] + rs2[t + 192];
    atomicAdd(&ws[WS_SUM_OFF + plane * 64 + c], s);
    atomicAdd(&ws[WS_SUMSQ_OFF + plane * 64 + c], s2);
  }
}

__global__ void finalize_kernel(const float* __restrict__ gamma,
                                const float* __restrict__ beta,
                                float* __restrict__ ws) {
  int i = threadIdx.x;
  if (i < 192) {
    int c = i & 63;
    float mu = ws[WS_SUM_OFF + i] * (1.0f / 16384.0f);
    float var = ws[WS_SUMSQ_OFF + i] * (1.0f / 16384.0f) - mu * mu;
    var = fmaxf(var, 0.0f);
    float rstd = 1.0f / sqrtf(var + BN_EPS);
    float sc = gamma[c] * rstd;
    ws[WS_SCALE_OFF + i] = sc;
    ws[WS_SHIFT_OFF + i] = beta[c] - mu * sc;
  }
}

// ================= apply BN + relu + add pooled, pack plane fp16 HWC
__global__ __launch_bounds__(256) void apply_kernel(float* __restrict__ ws,
                                                    __half* __restrict__ planes) {
  int idx = blockIdx.x * 256 + threadIdx.x;  // < 3145728
  int c = idx & 63;
  int pl = idx >> 20;  // 16384*64 = 2^20
  float sc = ws[WS_SCALE_OFF + pl * 64 + c];
  float sh = ws[WS_SHIFT_OFF + pl * 64 + c];
  float v = fmaf(ws[WS_CONV_OFF + idx], sc, sh);
  v = fmaxf(v, 0.0f) + ws[WS_POOL_OFF + idx];
  planes[idx] = __float2half(v);
}

// ================= bicubic sampling, 3 planes fused
__device__ __forceinline__ void cubic_w(float t, float w[4]) {
  float t1 = t + 1.0f;
  w[0] = ((A_COEF * t1 - 5.0f * A_COEF) * t1 + 8.0f * A_COEF) * t1 - 4.0f * A_COEF;
  w[1] = ((A_COEF + 2.0f) * t - (A_COEF + 3.0f)) * t * t + 1.0f;
  float s = 1.0f - t;
  w[2] = ((A_COEF + 2.0f) * s - (A_COEF + 3.0f)) * s * s + 1.0f;
  w[3] = 1.0f - w[0] - w[1] - w[2];
}

// wave = 8 points x 8 lanes; lane handles 8 channels (int4 = 8 fp16 per tap).
// grid: 500000/32 = 15625 blocks of 256.
__global__ __launch_bounds__(256) void sample_kernel(const float* __restrict__ coords,
                                                     const float* __restrict__ noise,
                                                     const __half* __restrict__ planes,
                                                     float* __restrict__ out) {
  const int t = threadIdx.x;
  const int wv = t >> 6, lane = t & 63;
  const int g = lane >> 3, l = lane & 7;
  const int n = blockIdx.x * 32 + wv * 8 + g;

  const float c0 = (coords[n * 3 + 0] + 1.0f) * 0.5f;
  const float c1 = (coords[n * 3 + 1] + 1.0f) * 0.5f;
  const float c2 = (coords[n * 3 + 2] + 1.0f) * 0.5f;

  float acc[8];
#pragma unroll
  for (int e = 0; e < 8; e++) acc[e] = 0.0f;

#pragma unroll
  for (int p = 0; p < 3; p++) {
    float u = (p == 1) ? c1 : c0;   // p0:(c0,c1) p1:(c1,c2) p2:(c0,c2)
    float v = (p == 0) ? c1 : c2;
    u += noise[(p * N_POINTS + n) * 2 + 0];
    v += noise[(p * N_POINTS + n) * 2 + 1];
    float gx = fminf(fmaxf(fmaf(u, 63.5f, 63.5f), 0.0f), 127.0f);
    float gy = fminf(fmaxf(fmaf(v, 63.5f, 63.5f), 0.0f), 127.0f);
    float x0f = floorf(gx), y0f = floorf(gy);
    float tx = gx - x0f, ty = gy - y0f;
    int ix = (int)x0f, iy = (int)y0f;
    float wx[4], wy[4];
    cubic_w(tx, wx);
    cubic_w(ty, wy);
    const __half* pb = planes + p * (128 * 128 * 64) + l * 8;
#pragma unroll
    for (int i = 0; i < 4; i++) {
      int yc = min(max(iy - 1 + i, 0), 127);
      const __half* rp = pb + yc * (128 * 64);
#pragma unroll
      for (int j = 0; j < 4; j++) {
        int xc = min(max(ix - 1 + j, 0), 127);
        union { int4 i4; __half2 h2[4]; } ub;
        ub.i4 = *reinterpret_cast<const int4*>(rp + xc * 64);
        float w = wy[i] * wx[j];
#pragma unroll
        for (int q = 0; q < 4; q++) {
          float2 f = __half22float2(ub.h2[q]);
          acc[2 * q]     = fmaf(f.x, w, acc[2 * q]);
          acc[2 * q + 1] = fmaf(f.y, w, acc[2 * q + 1]);
        }
      }
    }
  }
  float4* op = reinterpret_cast<float4*>(out + (size_t)n * 64 + l * 8);
  op[0] = make_float4(acc[0], acc[1], acc[2], acc[3]);
  op[1] = make_float4(acc[4], acc[5], acc[6], acc[7]);
}

extern "C" void kernel_launch(void* const* d_in, const int* in_sizes, int n_in,
                              void* d_out, int out_size, void* d_ws, size_t ws_size,
                              hipStream_t stream) {
  const float* coords = (const float*)d_in[0];
  const float* noise  = (const float*)d_in[1];
  const float* px     = (const float*)d_in[2];
  const float* py     = (const float*)d_in[3];
  const float* pz     = (const float*)d_in[4];
  const float* conv_w = (const float*)d_in[5];
  const float* conv_b = (const float*)d_in[6];
  const float* gamma  = (const float*)d_in[7];
  const float* beta   = (const float*)d_in[8];
  float* out = (float*)d_out;
  float* ws = (float*)d_ws;
  __half* planes = (__half*)(ws + WS_PLANES_OFF);

  prep_kernel<<<144, 256, 0, stream>>>(conv_w, ws);
  conv_kernel<<<dim3(2, 128, 3), 256, 0, stream>>>(px, py, pz, conv_b, ws);
  pool_kernel<<<dim3(128, 3), 256, 0, stream>>>(px, py, pz, ws);
  stats_kernel<<<192, 256, 0, stream>>>(ws);
  finalize_kernel<<<1, 256, 0, stream>>>(gamma, beta, ws);
  apply_kernel<<<12288, 256, 0, stream>>>(ws, planes);
  sample_kernel<<<15625, 256, 0, stream>>>(coords, noise, planes, out);
}

// Round 2
// 366.381 us; speedup vs baseline: 1.5620x; 1.5620x over previous
//
#include <hip/hip_runtime.h>
#include <hip/hip_fp16.h>

#define N_POINTS 500000
#define BN_EPS 1e-5f
#define A_COEF -0.75f

typedef __attribute__((ext_vector_type(8))) short short8;
typedef __attribute__((ext_vector_type(4))) float floatx4;
typedef unsigned short ushort_t;
typedef unsigned int uint_t;

// -------- workspace layout (float offsets) --------
#define WS_WBF_OFF    0                          // bf16 weights [tap(9)][oc(64)][ic(64)]   : 18432 floats
#define WS_CONV_OFF   18432                      // conv HWC fp32 [3][128][128][64]          : 3145728
#define WS_SUM_OFF    (WS_CONV_OFF + 3145728)    // [3][64]                                  : 192
#define WS_SUMSQ_OFF  (WS_SUM_OFF + 192)
#define WS_SCALE_OFF  (WS_SUMSQ_OFF + 192)
#define WS_SHIFT_OFF  (WS_SCALE_OFF + 192)
#define WS_PLANES_OFF (WS_SHIFT_OFF + 192)       // fp16 planes HWC [3][128][128][64]        : 1572864 floats
#define WS_INBF_OFF   (WS_PLANES_OFF + 1572864)  // bf16 input HWC [3][256][256][64]         : 6291456 floats
// total ~44.1 MB

__device__ __forceinline__ ushort_t f2bf(float f) {
  uint_t u = __float_as_uint(f);
  uint_t r = (u + 0x7fffu + ((u >> 16) & 1u)) >> 16;
  return (ushort_t)r;
}
__device__ __forceinline__ float bf2f(ushort_t u) {
  return __uint_as_float(((uint_t)u) << 16);
}

// ================= prep: weights [oc][ic][3][3] fp32 -> [tap][oc][ic] bf16; zero stat accums
__global__ __launch_bounds__(256) void wprep_kernel(const float* __restrict__ w_in,
                                                    float* __restrict__ ws) {
  int i = blockIdx.x * 256 + threadIdx.x;  // < 36864
  if (i < 36864) {
    int ic = i & 63;
    int oc = (i >> 6) & 63;
    int kk = i >> 12;  // 0..8
    ((ushort_t*)(ws + WS_WBF_OFF))[i] = f2bf(w_in[(oc * 64 + ic) * 9 + kk]);
  }
  if (i < 384) ws[WS_SUM_OFF + i] = 0.0f;  // sums + sumsq contiguous
}

// ================= transpose: input CHW fp32 -> HWC bf16
// grid (4, 256, 3): x-tile, row y, plane
__global__ __launch_bounds__(256) void transpose_kernel(const float* __restrict__ p0,
                                                        const float* __restrict__ p1,
                                                        const float* __restrict__ p2,
                                                        float* __restrict__ ws) {
  __shared__ float tile[64][65];
  const int xt = blockIdx.x, y = blockIdx.y, pl = blockIdx.z;
  const float* src = (pl == 0) ? p0 : ((pl == 1) ? p1 : p2);
  ushort_t* dst = (ushort_t*)(ws + WS_INBF_OFF) + pl * (256 * 256 * 64);
  const int t = threadIdx.x;
  const int x0 = xt * 64;
  for (int i = t; i < 4096; i += 256) {
    int c = i >> 6, x = i & 63;
    tile[x][c] = src[(c * 256 + y) * 256 + x0 + x];
  }
  __syncthreads();
  uint_t* du = (uint_t*)dst;
  for (int i = t; i < 2048; i += 256) {
    int x = i >> 5, cp = (i & 31) * 2;
    uint_t lo = f2bf(tile[x][cp]);
    uint_t hi = f2bf(tile[x][cp + 1]);
    du[((y * 256 + x0 + x) * 64 + cp) >> 1] = (hi << 16) | lo;
  }
}

// ================= conv3x3 stride2 pad1 via MFMA bf16 (bias dropped: cancels in batch-stat BN)
// grid (2, 128, 3). 4 waves; wave computes 16 px x 64 oc. A from global HWC bf16, B from bf16 weights.
__global__ __launch_bounds__(256) void conv_mfma_kernel(const float* __restrict__ ws_r,
                                                        float* __restrict__ ws) {
  const int xh = blockIdx.x, oy = blockIdx.y, pz = blockIdx.z;
  const int t = threadIdx.x;
  const int wv = t >> 6, lane = t & 63;
  const int mn = lane & 15;   // A: px row m ; B: oc col n
  const int kg = lane >> 4;   // k-group (k = kg*8 + j)
  const int x0w = xh * 64 + wv * 16;

  const ushort_t* inb = (const ushort_t*)(ws_r + WS_INBF_OFF) + pz * (256 * 256 * 64);
  const ushort_t* wbf = (const ushort_t*)(ws_r + WS_WBF_OFF);

  floatx4 acc[4] = {{0.f,0.f,0.f,0.f},{0.f,0.f,0.f,0.f},{0.f,0.f,0.f,0.f},{0.f,0.f,0.f,0.f}};

  for (int ky = 0; ky < 3; ky++) {
    int y = 2 * oy - 1 + ky;
    if (y < 0) continue;  // y <= 255 always
    const ushort_t* rowp = inb + y * (256 * 64);
    for (int kx = 0; kx < 3; kx++) {
      int xm = 2 * (x0w + mn) - 1 + kx;     // only -1 can be OOB (max 255)
      bool vx = xm >= 0;
      int xc = vx ? xm : 0;
      const ushort_t* abase = rowp + xc * 64 + kg * 8;
      const ushort_t* wbase = wbf + ((ky * 3 + kx) * 64 + mn) * 64 + kg * 8;
#pragma unroll
      for (int kc = 0; kc < 2; kc++) {
        union { int4 i4; short8 s8; } au;
        au.i4 = *reinterpret_cast<const int4*>(abase + kc * 32);
        if (!vx) au.i4 = make_int4(0, 0, 0, 0);
#pragma unroll
        for (int nt = 0; nt < 4; nt++) {
          union { int4 i4; short8 s8; } bu;
          bu.i4 = *reinterpret_cast<const int4*>(wbase + nt * 1024 + kc * 32);
          acc[nt] = __builtin_amdgcn_mfma_f32_16x16x32_bf16(au.s8, bu.s8, acc[nt], 0, 0, 0);
        }
      }
    }
  }
  // D: col(oc) = lane&15, row(px) = (lane>>4)*4 + reg
  float* cout = ws + WS_CONV_OFF + ((pz * 128 + oy) * 128 + x0w) * 64;
#pragma unroll
  for (int nt = 0; nt < 4; nt++) {
#pragma unroll
    for (int r = 0; r < 4; r++) {
      cout[(kg * 4 + r) * 64 + nt * 16 + mn] = acc[nt][r];
    }
  }
}

// ================= BN stats: per (plane, channel) sum & sumsq over 16384 px
__global__ __launch_bounds__(256) void stats_kernel(float* __restrict__ ws) {
  const int b = blockIdx.x;
  const int plane = b >> 6, chunk = b & 63;
  const int t = threadIdx.x;
  const int c = t & 63, g = t >> 6;
  const float* base = ws + WS_CONV_OFF + plane * (16384 * 64);
  float s = 0.0f, s2 = 0.0f;
  const int row0 = chunk * 256 + g * 64;
  for (int i = 0; i < 64; i++) {
    float v = base[(row0 + i) * 64 + c];
    s += v;
    s2 = fmaf(v, v, s2);
  }
  __shared__ float rs[256], rs2[256];
  rs[t] = s; rs2[t] = s2;
  __syncthreads();
  if (t < 64) {
    s = rs[t] + rs[t + 64] + rs[t + 128] + rs[t + 192];
    s2 = rs2[t] + rs2[t + 64] + rs2[t + 128] + rs2[t + 192];
    atomicAdd(&ws[WS_SUM_OFF + plane * 64 + c], s);
    atomicAdd(&ws[WS_SUMSQ_OFF + plane * 64 + c], s2);
  }
}

__global__ void finalize_kernel(const float* __restrict__ gamma,
                                const float* __restrict__ beta,
                                float* __restrict__ ws) {
  int i = threadIdx.x;
  if (i < 192) {
    int c = i & 63;
    float mu = ws[WS_SUM_OFF + i] * (1.0f / 16384.0f);
    float var = ws[WS_SUMSQ_OFF + i] * (1.0f / 16384.0f) - mu * mu;
    var = fmaxf(var, 0.0f);
    float rstd = 1.0f / sqrtf(var + BN_EPS);
    float sc = gamma[c] * rstd;
    ws[WS_SCALE_OFF + i] = sc;
    ws[WS_SHIFT_OFF + i] = beta[c] - mu * sc;
  }
}

// ================= apply BN + relu + fused avgpool(3x3 s2 p1, count_include_pad) + pack fp16
// thread = (plane, px, 8-channel group); 393216 threads
__global__ __launch_bounds__(256) void apply_kernel(float* __restrict__ ws,
                                                    __half* __restrict__ planes) {
  int idx = blockIdx.x * 256 + threadIdx.x;  // < 393216
  int g = idx & 7;
  int p = (idx >> 3) & 16383;
  int pl = idx >> 17;
  int oy = p >> 7, ox = p & 127;
  int cb = g * 8;

  const float* conv = ws + WS_CONV_OFF;
  float4 a0 = *reinterpret_cast<const float4*>(conv + (size_t)idx * 8);
  float4 a1 = *reinterpret_cast<const float4*>(conv + (size_t)idx * 8 + 4);

  float sc[8], sh[8];
#pragma unroll
  for (int k = 0; k < 8; k++) {
    sc[k] = ws[WS_SCALE_OFF + pl * 64 + cb + k];
    sh[k] = ws[WS_SHIFT_OFF + pl * 64 + cb + k];
  }

  const ushort_t* inb = (const ushort_t*)(ws + WS_INBF_OFF) + pl * (256 * 256 * 64);
  float ps[8];
#pragma unroll
  for (int k = 0; k < 8; k++) ps[k] = 0.0f;
#pragma unroll
  for (int r = 0; r < 3; r++) {
    int yy = 2 * oy - 1 + r;
    if (yy < 0) continue;  // <= 255 always
#pragma unroll
    for (int s = 0; s < 3; s++) {
      int xx = 2 * ox - 1 + s;
      if (xx < 0) continue;
      union { int4 i4; ushort_t u[8]; } ub;
      ub.i4 = *reinterpret_cast<const int4*>(inb + (yy * 256 + xx) * 64 + cb);
#pragma unroll
      for (int k = 0; k < 8; k++) ps[k] += bf2f(ub.u[k]);
    }
  }

  float v[8] = {a0.x, a0.y, a0.z, a0.w, a1.x, a1.y, a1.z, a1.w};
  union { int4 i4; __half h[8]; } ob;
#pragma unroll
  for (int k = 0; k < 8; k++) {
    float r = fmaxf(fmaf(v[k], sc[k], sh[k]), 0.0f) + ps[k] * (1.0f / 9.0f);
    ob.h[k] = __float2half(r);
  }
  *reinterpret_cast<int4*>(planes + (size_t)idx * 8) = ob.i4;
}

// ================= bicubic sampling, 3 planes fused
__device__ __forceinline__ void cubic_w(float t, float w[4]) {
  float t1 = t + 1.0f;
  w[0] = ((A_COEF * t1 - 5.0f * A_COEF) * t1 + 8.0f * A_COEF) * t1 - 4.0f * A_COEF;
  w[1] = ((A_COEF + 2.0f) * t - (A_COEF + 3.0f)) * t * t + 1.0f;
  float s = 1.0f - t;
  w[2] = ((A_COEF + 2.0f) * s - (A_COEF + 3.0f)) * s * s + 1.0f;
  w[3] = 1.0f - w[0] - w[1] - w[2];
}

__global__ __launch_bounds__(256) void sample_kernel(const float* __restrict__ coords,
                                                     const float* __restrict__ noise,
                                                     const __half* __restrict__ planes,
                                                     float* __restrict__ out) {
  const int t = threadIdx.x;
  const int wv = t >> 6, lane = t & 63;
  const int g = lane >> 3, l = lane & 7;
  const int n = blockIdx.x * 32 + wv * 8 + g;

  const float c0 = (coords[n * 3 + 0] + 1.0f) * 0.5f;
  const float c1 = (coords[n * 3 + 1] + 1.0f) * 0.5f;
  const float c2 = (coords[n * 3 + 2] + 1.0f) * 0.5f;

  float acc[8];
#pragma unroll
  for (int e = 0; e < 8; e++) acc[e] = 0.0f;

#pragma unroll
  for (int p = 0; p < 3; p++) {
    float u = (p == 1) ? c1 : c0;   // p0:(c0,c1) p1:(c1,c2) p2:(c0,c2)
    float v = (p == 0) ? c1 : c2;
    u += noise[(p * N_POINTS + n) * 2 + 0];
    v += noise[(p * N_POINTS + n) * 2 + 1];
    float gx = fminf(fmaxf(fmaf(u, 63.5f, 63.5f), 0.0f), 127.0f);
    float gy = fminf(fmaxf(fmaf(v, 63.5f, 63.5f), 0.0f), 127.0f);
    float x0f = floorf(gx), y0f = floorf(gy);
    float tx = gx - x0f, ty = gy - y0f;
    int ix = (int)x0f, iy = (int)y0f;
    float wx[4], wy[4];
    cubic_w(tx, wx);
    cubic_w(ty, wy);
    const __half* pb = planes + p * (128 * 128 * 64) + l * 8;
#pragma unroll
    for (int i = 0; i < 4; i++) {
      int yc = min(max(iy - 1 + i, 0), 127);
      const __half* rp = pb + yc * (128 * 64);
#pragma unroll
      for (int j = 0; j < 4; j++) {
        int xc = min(max(ix - 1 + j, 0), 127);
        union { int4 i4; __half2 h2[4]; } ub;
        ub.i4 = *reinterpret_cast<const int4*>(rp + xc * 64);
        float w = wy[i] * wx[j];
#pragma unroll
        for (int q = 0; q < 4; q++) {
          float2 f = __half22float2(ub.h2[q]);
          acc[2 * q]     = fmaf(f.x, w, acc[2 * q]);
          acc[2 * q + 1] = fmaf(f.y, w, acc[2 * q + 1]);
        }
      }
    }
  }
  float4* op = reinterpret_cast<float4*>(out + (size_t)n * 64 + l * 8);
  op[0] = make_float4(acc[0], acc[1], acc[2], acc[3]);
  op[1] = make_float4(acc[4], acc[5], acc[6], acc[7]);
}

extern "C" void kernel_launch(void* const* d_in, const int* in_sizes, int n_in,
                              void* d_out, int out_size, void* d_ws, size_t ws_size,
                              hipStream_t stream) {
  const float* coords = (const float*)d_in[0];
  const float* noise  = (const float*)d_in[1];
  const float* px     = (const float*)d_in[2];
  const float* py     = (const float*)d_in[3];
  const float* pz     = (const float*)d_in[4];
  const float* conv_w = (const float*)d_in[5];
  // conv_b (d_in[6]) unused: bias cancels exactly under batch-stat BN
  const float* gamma  = (const float*)d_in[7];
  const float* beta   = (const float*)d_in[8];
  float* out = (float*)d_out;
  float* ws = (float*)d_ws;
  __half* planes = (__half*)(ws + WS_PLANES_OFF);

  wprep_kernel<<<144, 256, 0, stream>>>(conv_w, ws);
  transpose_kernel<<<dim3(4, 256, 3), 256, 0, stream>>>(px, py, pz, ws);
  conv_mfma_kernel<<<dim3(2, 128, 3), 256, 0, stream>>>(ws, ws);
  stats_kernel<<<192, 256, 0, stream>>>(ws);
  finalize_kernel<<<1, 256, 0, stream>>>(gamma, beta, ws);
  apply_kernel<<<1536, 256, 0, stream>>>(ws, planes);
  sample_kernel<<<15625, 256, 0, stream>>>(coords, noise, planes, out);
}